// Round 1
// 520.301 us; speedup vs baseline: 1.2823x; 1.2823x over previous
//
#include <hip/hip_runtime.h>

// Grouped-dequant GEMM: Y[m,o] = sum_k X[m,k] * W[o,k] * S[o,k/128] + bias[o]
// M=8192, N=O=4096, K=I=4096, G=128. Harness promotes fp16 tensors to f32.
//
// R6: (a) dequant fused into the W f32->bf16 convert (removes the per-group
//     rescale from the GEMM K-loop entirely); (b) GEMM rebuilt on the 256^2
//     8-phase counted-vmcnt template (T2+T3+T4+T5): BM=BN=256, BK=64, 8 waves
//     (2x4), 128 KiB LDS double-buffer, per phase {ds_read subtile; issue one
//     half-tile global_load_lds; barrier; lgkmcnt(0); setprio(1); 16 MFMA;
//     setprio(0); barrier}; vmcnt(4) only at phases 4/8 (counted, never 0 in
//     steady state). LDS chunk-XOR swizzle: slot(r,c)=c^(r&7), achieved with
//     linear DMA dest + pre-swizzled global source (lane l fetches chunk
//     (l&7)^(l>>3)), swizzled ds_read_b128 on the consume side.
//
// Staging schedule (iteration computes tile P from buf0 in ph1-4, tile Q=P+1
// from buf1 in ph5-8; all issues >= 1 full phase after the region's last read):
//   ph1: Q.A0   ph2: Q.A1   ph3: (P+2).B0   ph4: (P+2).B1   [vmcnt(4)]
//   ph5: (P+2).A0  ph6: (P+2).A1  ph7: (Q+2).B0  ph8: (Q+2).B1  [vmcnt(4)]
// vmcnt(4)@ph4 leaves only (P+2).B0/B1 outstanding -> tile Q fully landed
// before ph5 reads it. Last iteration (no P+2) drains with vmcnt(0)@ph4.

typedef short bf16x8 __attribute__((ext_vector_type(8)));
typedef float f32x4 __attribute__((ext_vector_type(4)));
typedef int   i32x4 __attribute__((ext_vector_type(4)));

#define BM 128
#define BN 128
#define BK 64

__device__ __forceinline__ unsigned pk_bf16_rne(float x, float y) {
    unsigned a = __float_as_uint(x), b = __float_as_uint(y);
    a = a + 0x7FFFu + ((a >> 16) & 1u);          // round-to-nearest-even
    b = b + 0x7FFFu + ((b >> 16) & 1u);
    return (b & 0xFFFF0000u) | (a >> 16);
}

// ---- f32 -> bf16 bulk convert for X (8 f32 -> 16B per thread) ----
__global__ __launch_bounds__(256) void cvt_f32_bf16(
    const float* __restrict__ src, unsigned short* __restrict__ dst, long n)
{
    long i = (long)(blockIdx.x) * blockDim.x + threadIdx.x;   // units of 8 elts
    const long n8 = n >> 3;
    const long stride = (long)gridDim.x * blockDim.x;
    for (; i < n8; i += stride) {
        f32x4 a = *(const f32x4*)(src + i * 8);
        f32x4 b = *(const f32x4*)(src + i * 8 + 4);
        i32x4 o;
        o.x = pk_bf16_rne(a.x, a.y);
        o.y = pk_bf16_rne(a.z, a.w);
        o.z = pk_bf16_rne(b.x, b.y);
        o.w = pk_bf16_rne(b.z, b.w);
        *(i32x4*)(dst + i * 8) = o;
    }
}

// ---- W convert with fused dequant: Wb[o,i] = bf16(W[o,i] * S[o, i>>7]) ----
// 8 consecutive elements always lie inside one 128-wide scale group.
__global__ __launch_bounds__(256) void cvt_w_scale_bf16(
    const float* __restrict__ src, const float* __restrict__ S,
    unsigned short* __restrict__ dst, int kshift, int groups, long n8)
{
    long i = (long)(blockIdx.x) * blockDim.x + threadIdx.x;
    const long stride = (long)gridDim.x * blockDim.x;
    for (; i < n8; i += stride) {
        const long flat = i << 3;
        const int o = (int)(flat >> kshift);
        const int g = (int)((flat & (((long)1 << kshift) - 1)) >> 7);
        const float s = S[(size_t)o * groups + g];
        f32x4 a = *(const f32x4*)(src + flat);
        f32x4 b = *(const f32x4*)(src + flat + 4);
        i32x4 out;
        out.x = pk_bf16_rne(a.x * s, a.y * s);
        out.y = pk_bf16_rne(a.z * s, a.w * s);
        out.z = pk_bf16_rne(b.x * s, b.y * s);
        out.w = pk_bf16_rne(b.z * s, b.w * s);
        *(i32x4*)(dst + flat) = out;
    }
}

// ---- 256x256 8-phase GEMM ----

// Stage one 128-row half-tile (2 x global_load_lds per thread; each instr
// covers 64 rows: wave w -> rows slab..slab+7, lane l -> row slab+(l>>3),
// swizzled source chunk (l&7)^(l>>3), linear LDS dest base+lane*16).
#define STAGE_HALF(gbase, ldsbuf, t, h)                                        \
    {                                                                          \
        _Pragma("unroll")                                                      \
        for (int s_ = 0; s_ < 2; ++s_) {                                       \
            const int slab_ = (h) * 128 + s_ * 64 + wave * 8;                  \
            __builtin_amdgcn_global_load_lds(                                  \
                (const __attribute__((address_space(1))) void*)                \
                    ((gbase) + (size_t)slab_ * K + (size_t)(t) * 64),          \
                (__attribute__((address_space(3))) void*)(&(ldsbuf)[slab_ * 64]), \
                16, 0, 0);                                                     \
        }                                                                      \
    }

#define LOAD_A(buf, mh)                                                        \
    {                                                                          \
        _Pragma("unroll")                                                      \
        for (int t_ = 0; t_ < 4; ++t_) {                                       \
            aF[t_ * 2 + 0] = *(const bf16x8*)&As[buf][aRow + ((mh) * 4 + t_) * 1024 + kOff0]; \
            aF[t_ * 2 + 1] = *(const bf16x8*)&As[buf][aRow + ((mh) * 4 + t_) * 1024 + kOff1]; \
        }                                                                      \
    }

#define LOAD_B(buf, nh, arr)                                                   \
    {                                                                          \
        _Pragma("unroll")                                                      \
        for (int t_ = 0; t_ < 2; ++t_) {                                       \
            arr[t_ * 2 + 0] = *(const bf16x8*)&Bsh[buf][bRow + ((nh) * 2 + t_) * 1024 + kOff0]; \
            arr[t_ * 2 + 1] = *(const bf16x8*)&Bsh[buf][bRow + ((nh) * 2 + t_) * 1024 + kOff1]; \
        }                                                                      \
    }

#define MFMA_Q(mh, nh, arr)                                                    \
    {                                                                          \
        __builtin_amdgcn_s_setprio(1);                                         \
        _Pragma("unroll")                                                      \
        for (int t_ = 0; t_ < 4; ++t_)                                         \
            _Pragma("unroll")                                                  \
            for (int n_ = 0; n_ < 2; ++n_) {                                   \
                acc[(mh) * 4 + t_][(nh) * 2 + n_] = __builtin_amdgcn_mfma_f32_16x16x32_bf16( \
                    aF[t_ * 2 + 0], arr[n_ * 2 + 0], acc[(mh) * 4 + t_][(nh) * 2 + n_], 0, 0, 0); \
                acc[(mh) * 4 + t_][(nh) * 2 + n_] = __builtin_amdgcn_mfma_f32_16x16x32_bf16( \
                    aF[t_ * 2 + 1], arr[n_ * 2 + 1], acc[(mh) * 4 + t_][(nh) * 2 + n_], 0, 0, 0); \
            }                                                                  \
        __builtin_amdgcn_s_setprio(0);                                         \
    }

#define PH_BAR1 __builtin_amdgcn_s_barrier();                                  \
    asm volatile("s_waitcnt lgkmcnt(0)" ::: "memory");
#define PH_BAR2 __builtin_amdgcn_s_barrier();

__global__ __launch_bounds__(512, 2) void gq_gemm256(
    const unsigned short* __restrict__ X,    // M x K bf16 bits
    const unsigned short* __restrict__ W,    // N x K bf16 bits, pre-dequantized
    const float* __restrict__ Bv,            // N
    float* __restrict__ Y,                   // M x N f32
    int M, int N, int K)
{
    __shared__ short As[2][256 * 64];        // 64 KiB
    __shared__ short Bsh[2][256 * 64];       // 64 KiB

    const int tid  = threadIdx.x;
    const int wave = tid >> 6;               // 0..7
    const int lane = tid & 63;
    const int wm   = wave >> 2;              // 0..1  (wave tile: 128 x 64)
    const int wn   = wave & 3;               // 0..3
    const int l15  = lane & 15;
    const int quad = lane >> 4;
    const int sw   = l15 & 7;                // row-derived swizzle key

    const int nTilesN = N >> 8;
    int wg = blockIdx.x;
    if ((gridDim.x & 7) == 0) {              // bijective XCD-aware swizzle (T1)
        const int cpx = gridDim.x >> 3;
        wg = (wg & 7) * cpx + (wg >> 3);
    }
    const int bm = wg / nTilesN;
    const int bn = wg % nTilesN;
    const int rowBase = bm << 8;
    const int colBase = bn << 8;

    const int lrow = lane >> 3;
    const int lcol = ((lane & 7) ^ lrow) * 8;              // pre-swizzled source
    const unsigned short* gXbase = X + (size_t)(rowBase + lrow) * K + lcol;
    const unsigned short* gWbase = W + (size_t)(colBase + lrow) * K + lcol;

    const int aRow  = (wm * 128 + l15) * 64;
    const int bRow  = (wn * 64 + l15) * 64;
    const int kOff0 = (quad ^ sw) * 8;                     // ks=0 chunk slot
    const int kOff1 = kOff0 ^ 32;                          // ks=1 (= slot^4)

    const int NT = K >> 6;                                 // 64 K-tiles

    f32x4 acc[8][4];
    #pragma unroll
    for (int i = 0; i < 8; ++i)
        #pragma unroll
        for (int j = 0; j < 4; ++j)
            acc[i][j] = (f32x4){0.f, 0.f, 0.f, 0.f};

    bf16x8 aF[8], bF0[4], bF1[4];

    // ---- prologue: T0 fully + T1.B0/B1 in flight ----
    STAGE_HALF(gWbase, Bsh[0], 0, 0);
    STAGE_HALF(gWbase, Bsh[0], 0, 1);
    STAGE_HALF(gXbase, As[0],  0, 0);
    STAGE_HALF(gXbase, As[0],  0, 1);
    STAGE_HALF(gWbase, Bsh[1], 1, 0);
    STAGE_HALF(gWbase, Bsh[1], 1, 1);
    asm volatile("s_waitcnt vmcnt(4)" ::: "memory");       // T0 landed
    __builtin_amdgcn_s_barrier();

    for (int it = 0; it < (NT >> 1); ++it) {
        const int P = it << 1;
        const bool gp2 = (P + 2) < NT;

        // ---------------- tile P from buf 0 ----------------
        // phase 1
        LOAD_A(0, 0); LOAD_B(0, 0, bF0);
        STAGE_HALF(gXbase, As[1], P + 1, 0);               // Q.A0
        PH_BAR1; MFMA_Q(0, 0, bF0); PH_BAR2;
        // phase 2
        LOAD_B(0, 1, bF1);
        STAGE_HALF(gXbase, As[1], P + 1, 1);               // Q.A1
        PH_BAR1; MFMA_Q(0, 1, bF1); PH_BAR2;
        // phase 3   (buf0 B reads done after ph2 -> safe to restage)
        LOAD_A(0, 1);
        if (gp2) STAGE_HALF(gWbase, Bsh[0], P + 2, 0);     // P2.B0
        PH_BAR1; MFMA_Q(1, 1, bF1); PH_BAR2;
        // phase 4
        if (gp2) STAGE_HALF(gWbase, Bsh[0], P + 2, 1);     // P2.B1
        PH_BAR1; MFMA_Q(1, 0, bF0);
        if (gp2) { asm volatile("s_waitcnt vmcnt(4)" ::: "memory"); }
        else     { asm volatile("s_waitcnt vmcnt(0)" ::: "memory"); }
        PH_BAR2;

        // ---------------- tile Q from buf 1 ----------------
        // phase 5   (buf0 A reads done after ph3 -> safe to restage)
        LOAD_A(1, 0); LOAD_B(1, 0, bF0);
        if (gp2) STAGE_HALF(gXbase, As[0], P + 2, 0);      // P2.A0
        PH_BAR1; MFMA_Q(0, 0, bF0); PH_BAR2;
        // phase 6
        LOAD_B(1, 1, bF1);
        if (gp2) STAGE_HALF(gXbase, As[0], P + 2, 1);      // P2.A1
        PH_BAR1; MFMA_Q(0, 1, bF1); PH_BAR2;
        // phase 7   (buf1 B reads done after ph6)
        LOAD_A(1, 1);
        if (gp2) STAGE_HALF(gWbase, Bsh[1], P + 3, 0);     // Q2.B0
        PH_BAR1; MFMA_Q(1, 1, bF1); PH_BAR2;
        // phase 8
        if (gp2) STAGE_HALF(gWbase, Bsh[1], P + 3, 1);     // Q2.B1
        PH_BAR1; MFMA_Q(1, 0, bF0);
        asm volatile("s_waitcnt vmcnt(4)" ::: "memory");
        PH_BAR2;
    }

    // ---- epilogue: Y = acc + bias ----
    #pragma unroll
    for (int nt = 0; nt < 4; ++nt) {
        const int col = colBase + wn * 64 + nt * 16 + l15;
        const float bf = Bv[col];
        #pragma unroll
        for (int mt = 0; mt < 8; ++mt) {
            const int row0 = rowBase + wm * 128 + mt * 16 + quad * 4;
            #pragma unroll
            for (int r = 0; r < 4; ++r)
                Y[(size_t)(row0 + r) * N + col] = acc[mt][nt][r] + bf;
        }
    }
}

// ---- Path B fallback: f32 inputs inline-converted, 128^2 tile (unchanged) ----
__global__ __launch_bounds__(256) void gq_gemm_f32in(
    const float* __restrict__ Xf, const float* __restrict__ Wf,
    const float* __restrict__ S, const float* __restrict__ Bv,
    float* __restrict__ Y, int M, int N, int K)
{
    __shared__ short As[BM * BK];
    __shared__ short Bs[BN * BK];

    const int tid  = threadIdx.x;
    const int wave = tid >> 6;
    const int lane = tid & 63;
    const int wm   = wave >> 1;
    const int wn   = wave & 1;
    const int l15  = lane & 15;
    const int quad = lane >> 4;
    const int sw   = l15 & 7;

    const int nTilesN = N / BN;
    const int bm = blockIdx.x / nTilesN;
    const int bn = blockIdx.x % nTilesN;
    const int rowBase = bm * BM;
    const int colBase = bn * BN;
    const int srow  = tid >> 3;
    const int scol  = (tid & 7) * 8;
    const int sslot = ((tid & 7) ^ (srow & 7)) * 8;
    const int groups = K >> 7;

    f32x4 acc[4][4];
    #pragma unroll
    for (int i = 0; i < 4; ++i)
        #pragma unroll
        for (int j = 0; j < 4; ++j)
            acc[i][j] = (f32x4){0.f, 0.f, 0.f, 0.f};

    float t_prev[4] = {1.f, 1.f, 1.f, 1.f};

    for (int k0 = 0; k0 < K; k0 += BK) {
        i32x4 ra[4], rb[4];
        #pragma unroll
        for (int i = 0; i < 4; ++i) {
            const int row = i * 32 + srow;
            const float* gA = Xf + (size_t)(rowBase + row) * K + (k0 + scol);
            const float* gB = Wf + (size_t)(colBase + row) * K + (k0 + scol);
            f32x4 a0 = *(const f32x4*)gA, a1 = *(const f32x4*)(gA + 4);
            f32x4 b0 = *(const f32x4*)gB, b1 = *(const f32x4*)(gB + 4);
            ra[i].x = pk_bf16_rne(a0.x, a0.y); ra[i].y = pk_bf16_rne(a0.z, a0.w);
            ra[i].z = pk_bf16_rne(a1.x, a1.y); ra[i].w = pk_bf16_rne(a1.z, a1.w);
            rb[i].x = pk_bf16_rne(b0.x, b0.y); rb[i].y = pk_bf16_rne(b0.z, b0.w);
            rb[i].z = pk_bf16_rne(b1.x, b1.y); rb[i].w = pk_bf16_rne(b1.z, b1.w);
        }
        if ((k0 & 127) == 0) {
            const int g = k0 >> 7;
            float r[4];
            #pragma unroll
            for (int nt = 0; nt < 4; ++nt) {
                const int o = colBase + wn * 64 + nt * 16 + l15;
                const float t_cur = S[(size_t)o * groups + g];
                r[nt] = t_prev[nt] / t_cur;
                t_prev[nt] = t_cur;
            }
            #pragma unroll
            for (int mt = 0; mt < 4; ++mt)
                #pragma unroll
                for (int nt = 0; nt < 4; ++nt)
                    #pragma unroll
                    for (int e = 0; e < 4; ++e)
                        acc[mt][nt][e] *= r[nt];
        }
        __syncthreads();
        #pragma unroll
        for (int i = 0; i < 4; ++i) {
            const int row = i * 32 + srow;
            *(i32x4*)&As[row * BK + sslot] = ra[i];
            *(i32x4*)&Bs[row * BK + sslot] = rb[i];
        }
        __syncthreads();
        #pragma unroll
        for (int ks = 0; ks < 2; ++ks) {
            const int kb = ((ks * 4 + quad) ^ sw) * 8;
            bf16x8 a[4], b[4];
            #pragma unroll
            for (int t = 0; t < 4; ++t)
                a[t] = *(const bf16x8*)&As[(wm * 64 + t * 16 + l15) * BK + kb];
            #pragma unroll
            for (int t = 0; t < 4; ++t)
                b[t] = *(const bf16x8*)&Bs[(wn * 64 + t * 16 + l15) * BK + kb];
            #pragma unroll
            for (int mt = 0; mt < 4; ++mt)
                #pragma unroll
                for (int nt = 0; nt < 4; ++nt)
                    acc[mt][nt] = __builtin_amdgcn_mfma_f32_16x16x32_bf16(
                        a[mt], b[nt], acc[mt][nt], 0, 0, 0);
        }
    }
    #pragma unroll
    for (int nt = 0; nt < 4; ++nt) {
        const int col = colBase + wn * 64 + nt * 16 + l15;
        const float tl = t_prev[nt];
        const float bf = Bv[col];
        #pragma unroll
        for (int mt = 0; mt < 4; ++mt) {
            const int row0 = rowBase + wm * 64 + mt * 16 + quad * 4;
            #pragma unroll
            for (int r = 0; r < 4; ++r)
                Y[(size_t)(row0 + r) * N + col] = acc[mt][nt][r] * tl + bf;
        }
    }
}

extern "C" void kernel_launch(void* const* d_in, const int* in_sizes, int n_in,
                              void* d_out, int out_size, void* d_ws, size_t ws_size,
                              hipStream_t stream) {
    const float* X  = (const float*)d_in[0];   // x      (B,S,I)  f32
    const float* W  = (const float*)d_in[1];   // weight (O,I)    f32
    const float* S  = (const float*)d_in[2];   // scales (O,I/G)  f32
    const float* Bv = (const float*)d_in[3];   // bias   (O,)     f32
    float* Y = (float*)d_out;

    const int O = in_sizes[3];                 // 4096
    const int K = in_sizes[1] / O;             // 4096
    const int M = in_sizes[0] / K;             // 8192

    const size_t nX = (size_t)M * K, nW = (size_t)O * K;
    const size_t wsNeeded = (nX + nW) * sizeof(unsigned short);
    const bool shapeOK = (M % 256 == 0) && (O % 256 == 0) && (K % 128 == 0) &&
                         ((K & (K - 1)) == 0);

    if (ws_size >= wsNeeded && shapeOK) {
        unsigned short* Xb = (unsigned short*)d_ws;
        unsigned short* Wb = Xb + nX;
        const int kshift = __builtin_ctz((unsigned)K);
        cvt_f32_bf16<<<(int)(nX >> 11), 256, 0, stream>>>(X, Xb, (long)nX);
        cvt_w_scale_bf16<<<(int)(nW >> 11), 256, 0, stream>>>(
            W, S, Wb, kshift, K >> 7, (long)(nW >> 3));
        gq_gemm256<<<dim3((M >> 8) * (O >> 8)), dim3(512), 0, stream>>>(
            Xb, Wb, Bv, Y, M, O, K);
    } else {
        gq_gemm_f32in<<<dim3((M / BM) * (O / BN)), 256, 0, stream>>>(
            X, W, S, Bv, Y, M, O, K);
    }
}